// Round 17
// baseline (601.215 us; speedup 1.0000x reference)
//
#include <hip/hip_runtime.h>
#include <cstdint>

// B=16, C=64, H=W=256. 3x3 convs via bf16 MFMA implicit GEMM.
// Round 17: conv1 moves to single-X-buffer 2-phase (46.6KB LDS -> 3 blocks/CU,
// 3 barrier groups hide each other's drains — conv02's proven mechanism;
// launch_bounds(256,3), 132 regs < 170 cap). k_tr rebuilt with an LDS tile
// (coalesced fp32 reads AND short8 NHWC writes). conv02/k_fin unchanged.
using short8  = __attribute__((ext_vector_type(8))) short;
using short4v = __attribute__((ext_vector_type(4))) short;
using f32x16  = __attribute__((ext_vector_type(16))) float;
using float4v = __attribute__((ext_vector_type(4))) float;
typedef unsigned short ushort_t;

#define CHUNK_ROW 520       // 65 macro-groups x 8 slots (16 ci)
#define CHUNK_SLOTS 1560    // 3 rows
#define BUF_SLOTS 1632      // padded (stage stripes overrun to 1617)
#define XSHW (BUF_SLOTS * 8)   // shorts per pixel buffer = 13056
#define WSHW (20 * 512)        // conv1: weight buffer (18 rows + 2 pad)
#define XB0 WSHW
#define DYN1 ((WSHW + XSHW) * 2)         // conv1: 46592 B -> 3 blocks/CU
#define WSHM (40 * 512)        // merged: 36 rows + 4 pad = 20480 shorts
#define XBM WSHM               // merged pixel buffer offset (shorts)
#define DYN02 ((WSHM + XSHW) * 2)        // merged: 67072 B -> 2 blocks/CU

__device__ __forceinline__ float lrelu(float x) { return x > 0.f ? x : 0.1f * x; }

__device__ __forceinline__ ushort_t f2bf(float f) {
    union { float f; unsigned u; } v; v.f = f;
    unsigned r = (v.u + 0x7FFFu + ((v.u >> 16) & 1u)) >> 16;
    return (ushort_t)r;
}
__device__ __forceinline__ float bf2f(ushort_t b) {
    union { unsigned u; float f; } v; v.u = ((unsigned)b) << 16; return v.f;
}

// async 16B global -> LDS (dest = wave-uniform base; HW adds lane*16)
__device__ __forceinline__ void gload_lds16(const ushort_t* g, ushort_t* l) {
    __builtin_amdgcn_global_load_lds(
        (const __attribute__((address_space(1))) void*)g,
        (__attribute__((address_space(3))) void*)l, 16, 0, 0);
}

#define VMCNT(n) asm volatile("s_waitcnt vmcnt(" #n ")" ::: "memory")
#define RBAR() __builtin_amdgcn_s_barrier()
#define SCHED0() __builtin_amdgcn_sched_barrier(0)

// ---------------------------------------------------------------------------
// Tiny branch: ktr[b][tap][c] = leaky(kern) * sigmoid-gate (mv folded in).
// ---------------------------------------------------------------------------
__global__ void k_tiny(const float* __restrict__ t, const float* __restrict__ tW1,
                       const float* __restrict__ tW2, const float* __restrict__ kW1,
                       const float* __restrict__ kW2, float* __restrict__ ktr) {
    int b = blockIdx.x;
    int c = threadIdx.x;  // 64
    __shared__ float h1[64], g1[64];
    float ts = t[b];
    h1[c] = lrelu(ts * tW1[c]);
    g1[c] = lrelu(ts * kW1[c]);
    __syncthreads();
    float s = 0.f;
    for (int j = 0; j < 64; ++j) s = fmaf(tW2[c * 64 + j], h1[j], s);
    float mvv = 1.f / (1.f + expf(-s));
    for (int q = 0; q < 9; ++q) {
        float s2 = 0.f;
        for (int j = 0; j < 64; ++j) s2 = fmaf(kW2[(c * 9 + q) * 64 + j], g1[j], s2);
        ktr[b * 576 + q * 64 + c] = lrelu(s2) * mvv;
    }
}

// ---------------------------------------------------------------------------
// Zero row buffer (edge-redirect source for staging).
// ---------------------------------------------------------------------------
__global__ void k_zrow(ushort_t* __restrict__ z) {
    int i = blockIdx.x * 256 + threadIdx.x;  // 2048 threads, 16384 shorts
    *(short8*)(z + (size_t)i * 8) = (short8)0;
}

// ---------------------------------------------------------------------------
// Pack weights, chunk-major.
// wpM: [chunk][row 0..35][lane][8]  rows 0-17: fW1, rows 18-35: cW (row=t*2+ct)
// wp2: [chunk][row 0..17][lane][8]  fW2.
//   element = W[co = ct*32+(lane&31)][ci = chunk*16+(lane>>5)*8+j], tap t
// ---------------------------------------------------------------------------
__global__ void k_pack(const float* __restrict__ w1, const float* __restrict__ w2,
                       const float* __restrict__ w3, ushort_t* __restrict__ wpM,
                       ushort_t* __restrict__ wp2) {
    int idx = blockIdx.x * 256 + threadIdx.x;
    const int NM = 4 * 36 * 512;
    if (idx >= NM + 4 * 18 * 512) return;
    const float* W;
    ushort_t* dst;
    int chunk, row, e;
    if (idx < NM) {
        chunk = idx / (36 * 512);
        int rem = idx % (36 * 512);
        row = rem / 512;
        e = rem % 512;
        W = (row < 18) ? w1 : w3;
        dst = wpM + idx;
        row %= 18;
    } else {
        int i2 = idx - NM;
        chunk = i2 / (18 * 512);
        int rem = i2 % (18 * 512);
        row = rem / 512;
        e = rem % 512;
        W = w2;
        dst = wp2 + i2;
    }
    int lane = e >> 3, j = e & 7;
    int t = row >> 1, ct = row & 1;
    int co = ct * 32 + (lane & 31);
    int ci = chunk * 16 + (lane >> 5) * 8 + j;
    *dst = f2bf(W[(co * 64 + ci) * 9 + t]);
}

// ---------------------------------------------------------------------------
// Transpose x: fp32 NCHW -> bf16 NHWC via LDS tile (coalesced both sides).
// Block = (b,h); 4 w-tiles of 64; tile [64c][66] bf16 (8.4KB).
// ---------------------------------------------------------------------------
__global__ __launch_bounds__(256) void k_tr(const float* __restrict__ x,
                                            ushort_t* __restrict__ xbf) {
    __shared__ ushort_t tl[64][66];
    int bid = blockIdx.x;
    int h = bid & 255, b = bid >> 8;
    int t = threadIdx.x;
    int cb = t >> 6;        // 0..3 (wave id)
    int wl = t & 63;        // lane
    for (int wt = 0; wt < 4; ++wt) {
        __syncthreads();
#pragma unroll
        for (int cc = 0; cc < 16; ++cc) {
            int c = cc * 4 + cb;
            float v = x[(((size_t)(b * 64 + c)) << 16) + h * 256 + wt * 64 + wl];
            tl[c][wl] = f2bf(v);
        }
        __syncthreads();
        int g = t & 7, w2 = t >> 3;  // 0..31
#pragma unroll
        for (int half = 0; half < 2; ++half) {
            int w = w2 + half * 32;
            short8 v;
#pragma unroll
            for (int j = 0; j < 8; ++j) v[j] = (short)tl[g * 8 + j][w];
            *(short8*)(xbf + (((size_t)(b * 256 + h) * 256 + wt * 64 + w) * 64 + g * 8)) = v;
        }
    }
}

// ---------------------------------------------------------------------------
// Stage one 16-ci pixel chunk: 3 rows x 258 pix, 7 x gload_lds16 per wave
// (4 waves, stripes of 390 slots). Inverse swizzle in per-lane source addr.
// ---------------------------------------------------------------------------
#define STAGE_X(chunk, xbase)                                                    \
    {                                                                            \
        _Pragma("unroll")                                                        \
        for (int i_ = 0; i_ < 7; ++i_) {                                         \
            int base_ = wv * 390 + i_ * 64;                                      \
            int S_ = base_ + lane;                                               \
            S_ = S_ < CHUNK_SLOTS ? S_ : CHUNK_SLOTS - 1;                        \
            int row_ = (S_ >= 2 * CHUNK_ROW) ? 2 : (S_ >= CHUNK_ROW ? 1 : 0);    \
            int rem_ = S_ - row_ * CHUNK_ROW;                                    \
            int mg_ = rem_ >> 3, sl_ = rem_ & 7;                                 \
            int sp_ = sl_ ^ (mg_ & 7);                                           \
            int p_ = mg_ * 4 + (sp_ >> 1), g_ = sp_ & 1;                         \
            int wsx_ = p_ - 1;                                                   \
            bool edge_ = (unsigned)wsx_ >= 256u;                                 \
            const ushort_t* rp_ = (row_ == 0) ? rb0 : (row_ == 1 ? rb1 : rb2);   \
            const ushort_t* src_ =                                               \
                edge_ ? zv : (rp_ + wsx_ * 64 + (chunk)*16 + g_ * 8);            \
            gload_lds16(src_, xs + (xbase) + (size_t)base_ * 8);                 \
        }                                                                        \
    }

// conv1: stage 18-row weight slice (5/wave, rows 18-19 pad dups).
#define STAGE_W(chunk)                                                           \
    {                                                                            \
        _Pragma("unroll")                                                        \
        for (int i_ = 0; i_ < 5; ++i_) {                                         \
            int row_ = wv * 5 + i_;                                              \
            int rc_ = row_ > 17 ? 17 : row_;                                     \
            gload_lds16(wp + (size_t)((chunk)*18 + rc_) * 512 + lane * 8,        \
                        xs + (size_t)row_ * 512);                                \
        }                                                                        \
    }

// merged: stage 36-row weight slice (10/wave, rows 36-39 pad dups).
#define STAGE_WM(chunk)                                                          \
    {                                                                            \
        _Pragma("unroll")                                                        \
        for (int i_ = 0; i_ < 10; ++i_) {                                        \
            int row_ = wv * 10 + i_;                                             \
            int rc_ = row_ > 35 ? 35 : row_;                                     \
            gload_lds16(wpM + (size_t)((chunk)*36 + rc_) * 512 + lane * 8,       \
                        xs + (size_t)row_ * 512);                                \
        }                                                                        \
    }

// conv1 compute: A rows 0..17, B from xbase. Pure-LDS cluster.
#define COMPUTE(xbase)                                                           \
    {                                                                            \
        __builtin_amdgcn_s_setprio(1);                                           \
        _Pragma("unroll")                                                        \
        for (int t_ = 0; t_ < 9; ++t_) {                                         \
            short8 a0 = *(const short8*)(xs + (size_t)(t_ * 2) * 512 + lane * 8);\
            short8 a1 = *(const short8*)(xs + (size_t)(t_ * 2 + 1) * 512 + lane * 8); \
            const int dwx_ = t_ % 3, rr_ = t_ / 3;                               \
            _Pragma("unroll")                                                    \
            for (int pt_ = 0; pt_ < 2; ++pt_) {                                  \
                int p_ = pw0 + pt_ * 32 + l31 + dwx_;                            \
                int mg_ = p_ >> 2;                                               \
                int sl_ = ((p_ & 3) * 2 + lhi) ^ (mg_ & 7);                      \
                short8 bf = *(const short8*)(                                    \
                    xs + (xbase) + (size_t)(rr_ * CHUNK_ROW + mg_ * 8 + sl_) * 8);\
                acc[0][pt_] = __builtin_amdgcn_mfma_f32_32x32x16_bf16(           \
                    a0, bf, acc[0][pt_], 0, 0, 0);                               \
                acc[1][pt_] = __builtin_amdgcn_mfma_f32_32x32x16_bf16(           \
                    a1, bf, acc[1][pt_], 0, 0, 0);                               \
            }                                                                    \
        }                                                                        \
        __builtin_amdgcn_s_setprio(0);                                           \
    }

// merged compute: A rows 0..17 (fW1) + 18..35 (cW); one B read -> 4 MFMAs.
#define COMPUTE_M()                                                              \
    {                                                                            \
        __builtin_amdgcn_s_setprio(1);                                           \
        _Pragma("unroll")                                                        \
        for (int t_ = 0; t_ < 9; ++t_) {                                         \
            short8 a0 = *(const short8*)(xs + (size_t)(t_ * 2) * 512 + lane * 8);\
            short8 a1 = *(const short8*)(xs + (size_t)(t_ * 2 + 1) * 512 + lane * 8); \
            short8 c0 = *(const short8*)(xs + (size_t)(18 + t_ * 2) * 512 + lane * 8); \
            short8 c1 = *(const short8*)(xs + (size_t)(19 + t_ * 2) * 512 + lane * 8); \
            const int dwx_ = t_ % 3, rr_ = t_ / 3;                               \
            _Pragma("unroll")                                                    \
            for (int pt_ = 0; pt_ < 2; ++pt_) {                                  \
                int p_ = pw0 + pt_ * 32 + l31 + dwx_;                            \
                int mg_ = p_ >> 2;                                               \
                int sl_ = ((p_ & 3) * 2 + lhi) ^ (mg_ & 7);                      \
                short8 bf = *(const short8*)(                                    \
                    xs + XBM + (size_t)(rr_ * CHUNK_ROW + mg_ * 8 + sl_) * 8);   \
                accA[0][pt_] = __builtin_amdgcn_mfma_f32_32x32x16_bf16(          \
                    a0, bf, accA[0][pt_], 0, 0, 0);                              \
                accA[1][pt_] = __builtin_amdgcn_mfma_f32_32x32x16_bf16(          \
                    a1, bf, accA[1][pt_], 0, 0, 0);                              \
                accC[0][pt_] = __builtin_amdgcn_mfma_f32_32x32x16_bf16(          \
                    c0, bf, accC[0][pt_], 0, 0, 0);                              \
                accC[1][pt_] = __builtin_amdgcn_mfma_f32_32x32x16_bf16(          \
                    c1, bf, accC[1][pt_], 0, 0, 0);                              \
            }                                                                    \
        }                                                                        \
        __builtin_amdgcn_s_setprio(0);                                           \
    }

// ---------------------------------------------------------------------------
// Merged conv0+conv2. Block = (b,h) XCD-swizzled, 4 waves, 64co x 64pix each.
// accA: fW1+fb1+leaky -> f1 bf16 NHWC. accC: cW+cb -> fp32 NCHW (d_out).
// 67KB LDS -> 2 blocks/CU hide each other's drains.
// ---------------------------------------------------------------------------
__global__ __launch_bounds__(256, 2) void k_conv02(
    const ushort_t* __restrict__ in, const ushort_t* __restrict__ zv,
    const ushort_t* __restrict__ wpM, const float* __restrict__ ba,
    const float* __restrict__ bc, ushort_t* __restrict__ f1out,
    float* __restrict__ cres) {
    extern __shared__ __align__(16) ushort_t xs[];  // [W 40 rows][X 1632 slots]
    const int tid = threadIdx.x;
    const int lane = tid & 63;
    const int wv = tid >> 6;  // 0..3
    const unsigned bid = blockIdx.x;
    const unsigned L = (bid & 7u) * 512u + (bid >> 3);  // 4096 = 8*512 bijective
    const int h = L & 255, b = L >> 8;
    const int l31 = lane & 31, lhi = lane >> 5;
    const int pw0 = wv * 64;

    const ushort_t* rb0 = (h > 0)   ? in + ((size_t)(b * 256 + h - 1)) * 16384 : zv;
    const ushort_t* rb1 =             in + ((size_t)(b * 256 + h)) * 16384;
    const ushort_t* rb2 = (h < 255) ? in + ((size_t)(b * 256 + h + 1)) * 16384 : zv;

    f32x16 accA[2][2], accC[2][2];
#pragma unroll
    for (int a = 0; a < 2; ++a)
#pragma unroll
        for (int c = 0; c < 2; ++c) { accA[a][c] = (f32x16)0.0f; accC[a][c] = (f32x16)0.0f; }

#pragma unroll
    for (int ch = 0; ch < 4; ++ch) {
        STAGE_WM(ch);
        STAGE_X(ch, XBM);
        VMCNT(0);
        RBAR(); SCHED0();
        COMPUTE_M();
        RBAR();  // protect W+X before next chunk's staging
    }

    // Epilogues. D layout: col(pix)=lane&31, row(co)=(reg&3)+8*(reg>>2)+4*(lane>>5)
    const int co_b = 4 * lhi;
    {   // conv0 -> f1 bf16 NHWC + leaky
        ushort_t* outb = f1out + ((size_t)(b * 256 + h)) * 16384;
#pragma unroll
        for (int ct = 0; ct < 2; ++ct)
#pragma unroll
            for (int pt = 0; pt < 2; ++pt) {
                int pix = pw0 + pt * 32 + l31;
                ushort_t* po = outb + (size_t)pix * 64 + ct * 32 + co_b;
#pragma unroll
                for (int q = 0; q < 4; ++q) {
                    float4v bv = *(const float4v*)(ba + ct * 32 + co_b + 8 * q);
                    short4v sv;
#pragma unroll
                    for (int m = 0; m < 4; ++m) {
                        float v = lrelu(accA[ct][pt][q * 4 + m] + bv[m]);
                        sv[m] = (short)f2bf(v);
                    }
                    *(short4v*)(po + 8 * q) = sv;
                }
            }
    }
    {   // conv2 -> d_out fp32 NCHW + cb
        float* pb = cres + (((size_t)b * 64) << 16) + h * 256;
#pragma unroll
        for (int ct = 0; ct < 2; ++ct)
#pragma unroll
            for (int pt = 0; pt < 2; ++pt) {
                int pix = pw0 + pt * 32 + l31;
#pragma unroll
                for (int q = 0; q < 4; ++q) {
                    float4v bv = *(const float4v*)(bc + ct * 32 + co_b + 8 * q);
#pragma unroll
                    for (int m = 0; m < 4; ++m) {
                        int c = ct * 32 + co_b + 8 * q + m;
                        pb[((size_t)c << 16) + pix] = accC[ct][pt][q * 4 + m] + bv[m];
                    }
                }
            }
    }
}

// ---------------------------------------------------------------------------
// conv1: single-X-buffer 2-phase, 46.6KB LDS -> 3 blocks/CU (3 barrier
// groups hide each other's drains). bf16 NHWC in -> leaky -> bf16 NCHW out.
// ---------------------------------------------------------------------------
__global__ __launch_bounds__(256, 3) void k_conv1(
    const ushort_t* __restrict__ in, const ushort_t* __restrict__ zv,
    const ushort_t* __restrict__ wp, const float* __restrict__ bias,
    ushort_t* __restrict__ outp) {
    extern __shared__ __align__(16) ushort_t xs[];  // [W 20 rows][X 1632 slots]
    const int tid = threadIdx.x;
    const int lane = tid & 63;
    const int wv = tid >> 6;  // 0..3
    const unsigned bid = blockIdx.x;
    const unsigned L = (bid & 7u) * 512u + (bid >> 3);
    const int h = L & 255, b = L >> 8;
    const int l31 = lane & 31, lhi = lane >> 5;
    const int pw0 = wv * 64;

    const ushort_t* rb0 = (h > 0)   ? in + ((size_t)(b * 256 + h - 1)) * 16384 : zv;
    const ushort_t* rb1 =             in + ((size_t)(b * 256 + h)) * 16384;
    const ushort_t* rb2 = (h < 255) ? in + ((size_t)(b * 256 + h + 1)) * 16384 : zv;

    f32x16 acc[2][2];
#pragma unroll
    for (int a = 0; a < 2; ++a)
#pragma unroll
        for (int c = 0; c < 2; ++c) acc[a][c] = (f32x16)0.0f;

#pragma unroll
    for (int ch = 0; ch < 4; ++ch) {
        STAGE_W(ch);
        STAGE_X(ch, XB0);
        VMCNT(0);
        RBAR(); SCHED0();
        COMPUTE(XB0);
        RBAR();  // protect W+X before next chunk's staging
    }

    const int co_b = 4 * lhi;
    // bf16 NCHW + leaky
    ushort_t* pb = outp + (((size_t)b * 64) << 16) + h * 256;
#pragma unroll
    for (int ct = 0; ct < 2; ++ct)
#pragma unroll
        for (int pt = 0; pt < 2; ++pt) {
            int pix = pw0 + pt * 32 + l31;
#pragma unroll
            for (int q = 0; q < 4; ++q) {
                float4v bv = *(const float4v*)(bias + ct * 32 + co_b + 8 * q);
#pragma unroll
                for (int m = 0; m < 4; ++m) {
                    int c = ct * 32 + co_b + 8 * q + m;
                    float v = lrelu(acc[ct][pt][q * 4 + m] + bv[m]);
                    pb[((size_t)c << 16) + pix] = f2bf(v);
                }
            }
        }
}

// ---------------------------------------------------------------------------
// Final depthwise: out[b][c][h][w] += sum_tap ktr[b][tap][c] * f2[b][c][h'][w']
// Block = (b, c, 8-row band); f2 is bf16 NCHW. High occupancy, ~roofline.
// ---------------------------------------------------------------------------
__global__ __launch_bounds__(256) void k_fin(const ushort_t* __restrict__ f2,
                                             const float* __restrict__ ktr,
                                             float* __restrict__ out) {
    __shared__ __align__(16) ushort_t s[10 * 272];
    const unsigned bid = blockIdx.x;
    const unsigned L = (bid & 7u) * 4096u + (bid >> 3);  // bijective, 32768=8*4096
    const int hb = L & 31, c = (L >> 5) & 63, b = L >> 11;
    const int h0 = hb * 8;
    const int w = threadIdx.x;

    const ushort_t* f2c = f2 + (((size_t)(b * 64 + c)) << 16);
    for (int i = w; i < 320; i += 256) {
        int r = i >> 5, seg = i & 31;
        int hs = h0 - 1 + r;
        short8 v = (short8)0;
        if ((unsigned)hs < 256u) v = *(const short8*)(f2c + hs * 256 + seg * 8);
        *(short8*)(&s[r * 272 + 8 + seg * 8]) = v;
        if (seg == 0) s[r * 272 + 7] = 0;
        if (seg == 31) s[r * 272 + 264] = 0;
    }
    __syncthreads();

    float kv[9];
#pragma unroll
    for (int t9 = 0; t9 < 9; ++t9) kv[t9] = ktr[b * 576 + t9 * 64 + c];

    float lv[10], cv[10], rv[10];
#pragma unroll
    for (int r = 0; r < 10; ++r) {
        lv[r] = bf2f(s[r * 272 + 7 + w]);
        cv[r] = bf2f(s[r * 272 + 8 + w]);
        rv[r] = bf2f(s[r * 272 + 9 + w]);
    }

    float* ob = out + (((size_t)(b * 64 + c)) << 16) + h0 * 256 + w;
#pragma unroll
    for (int rr = 0; rr < 8; ++rr) {
        float dwv = 0.f;
#pragma unroll
        for (int r3 = 0; r3 < 3; ++r3) {
            dwv = fmaf(kv[r3 * 3 + 0], lv[rr + r3], dwv);
            dwv = fmaf(kv[r3 * 3 + 1], cv[rr + r3], dwv);
            dwv = fmaf(kv[r3 * 3 + 2], rv[rr + r3], dwv);
        }
        float* po = ob + rr * 256;
        *po = *po + dwv;
    }
}

// ---------------------------------------------------------------------------
extern "C" void kernel_launch(void* const* d_in, const int* in_sizes, int n_in,
                              void* d_out, int out_size, void* d_ws, size_t ws_size,
                              hipStream_t stream) {
    const float* x   = (const float*)d_in[0];
    const float* t   = (const float*)d_in[1];
    const float* tW1 = (const float*)d_in[2];
    const float* tW2 = (const float*)d_in[3];
    const float* fW1 = (const float*)d_in[4];
    const float* fb1 = (const float*)d_in[5];
    const float* fW2 = (const float*)d_in[6];
    const float* fb2 = (const float*)d_in[7];
    const float* kW1 = (const float*)d_in[8];
    const float* kW2 = (const float*)d_in[9];
    const float* cW  = (const float*)d_in[10];
    const float* cb  = (const float*)d_in[11];

    // ws: [ktr 36K @0][wpM 144K @65536][wp2 72K @212992][zv 32K @294912]
    //     [R1 128MB @512K]: xbf (until conv02 done), then f2
    //     [R2 128MB @512K+128MB]: f1
    char* ws = (char*)d_ws;
    float*    ktr  = (float*)ws;
    ushort_t* wpM  = (ushort_t*)(ws + 65536);
    ushort_t* wp2  = wpM + 4 * 36 * 512;
    ushort_t* zv   = (ushort_t*)(ws + 294912);
    ushort_t* xbf  = (ushort_t*)(ws + (512u << 10));                       // R1
    ushort_t* f1bf = (ushort_t*)(ws + (512u << 10) + ((size_t)128 << 20)); // R2
    ushort_t* f2n  = xbf;  // R1 reused: xbf dead after k_conv02
    float*    out  = (float*)d_out;

    hipFuncSetAttribute(reinterpret_cast<const void*>(&k_conv02),
                        hipFuncAttributeMaxDynamicSharedMemorySize, DYN02);
    hipFuncSetAttribute(reinterpret_cast<const void*>(&k_conv1),
                        hipFuncAttributeMaxDynamicSharedMemorySize, DYN1);

    k_tiny<<<dim3(16), dim3(64), 0, stream>>>(t, tW1, tW2, kW1, kW2, ktr);
    k_zrow<<<dim3(8), dim3(256), 0, stream>>>(zv);
    k_pack<<<dim3((4 * 36 * 512 + 4 * 18 * 512 + 255) / 256), dim3(256), 0, stream>>>(
        fW1, fW2, cW, wpM, wp2);
    k_tr<<<dim3(4096), dim3(256), 0, stream>>>(x, xbf);

    // conv02: x -> f1 (bf16 NHWC, R2) + d_out (fp32 NCHW, +cb);
    // conv1: f1 -> f2 (bf16 NCHW, R1); k_fin: out += dw(f2)*gate.
    k_conv02<<<dim3(4096), dim3(256), DYN02, stream>>>(
        xbf, zv, wpM, fb1, cb, f1bf, out);
    k_conv1<<<dim3(4096), dim3(256), DYN1, stream>>>(f1bf, zv, wp2, fb2, f2n);
    k_fin<<<dim3(32768), dim3(256), 0, stream>>>(f2n, ktr, out);
}

// Round 18
// 594.954 us; speedup vs baseline: 1.0105x; 1.0105x over previous
//
#include <hip/hip_runtime.h>
#include <cstdint>

// B=16, C=64, H=W=256. 3x3 convs via bf16 MFMA implicit GEMM.
// Round 18: base = round 16 (best measured, 586us: conv02 merged 2-phase +
// double-buffered conv1 + gather k_tr + k_fin). Single change: conv1 at
// HALF WIDTH — block = (b,h,half), 8192 blocks, 4 waves x (64co x 32px),
// LDS 48KB -> 3 blocks/CU with the counted-vmcnt double-buffer kept.
using short8  = __attribute__((ext_vector_type(8))) short;
using short4v = __attribute__((ext_vector_type(4))) short;
using f32x16  = __attribute__((ext_vector_type(16))) float;
using float4v = __attribute__((ext_vector_type(4))) float;
typedef unsigned short ushort_t;

#define CHUNK_ROW 520       // full-width: 65 mg x 8 slots (16 ci)
#define CHUNK_SLOTS 1560    // 3 rows
#define BUF_SLOTS 1632      // padded
#define XSHW (BUF_SLOTS * 8)   // full-width pixel buffer shorts = 13056
#define WSHM (40 * 512)        // merged: 36 rows + 4 pad = 20480 shorts
#define XBM WSHM               // merged pixel buffer offset (shorts)
#define DYN02 ((WSHM + XSHW) * 2)        // merged: 67072 B -> 2 blocks/CU

// conv1 half-width geometry
#define HROW 264            // 33 mg x 8 slots
#define HCHS 792            // 3 rows
#define HBUF 896            // padded (stripes overrun to 855)
#define HXSH (HBUF * 8)     // 7168 shorts per buffer
#define WH   (20 * 512)     // 18-row weight slice + 2 pad = 10240 shorts
#define HXB0 WH
#define HXB1 (WH + HXSH)
#define DYN1 ((WH + 2 * HXSH) * 2)       // 49152 B -> 3 blocks/CU

__device__ __forceinline__ float lrelu(float x) { return x > 0.f ? x : 0.1f * x; }

__device__ __forceinline__ ushort_t f2bf(float f) {
    union { float f; unsigned u; } v; v.f = f;
    unsigned r = (v.u + 0x7FFFu + ((v.u >> 16) & 1u)) >> 16;
    return (ushort_t)r;
}
__device__ __forceinline__ float bf2f(ushort_t b) {
    union { unsigned u; float f; } v; v.u = ((unsigned)b) << 16; return v.f;
}

// async 16B global -> LDS (dest = wave-uniform base; HW adds lane*16)
__device__ __forceinline__ void gload_lds16(const ushort_t* g, ushort_t* l) {
    __builtin_amdgcn_global_load_lds(
        (const __attribute__((address_space(1))) void*)g,
        (__attribute__((address_space(3))) void*)l, 16, 0, 0);
}

#define VMCNT(n) asm volatile("s_waitcnt vmcnt(" #n ")" ::: "memory")
#define RBAR() __builtin_amdgcn_s_barrier()
#define SCHED0() __builtin_amdgcn_sched_barrier(0)

// ---------------------------------------------------------------------------
// Tiny branch: ktr[b][tap][c] = leaky(kern) * sigmoid-gate (mv folded in).
// ---------------------------------------------------------------------------
__global__ void k_tiny(const float* __restrict__ t, const float* __restrict__ tW1,
                       const float* __restrict__ tW2, const float* __restrict__ kW1,
                       const float* __restrict__ kW2, float* __restrict__ ktr) {
    int b = blockIdx.x;
    int c = threadIdx.x;  // 64
    __shared__ float h1[64], g1[64];
    float ts = t[b];
    h1[c] = lrelu(ts * tW1[c]);
    g1[c] = lrelu(ts * kW1[c]);
    __syncthreads();
    float s = 0.f;
    for (int j = 0; j < 64; ++j) s = fmaf(tW2[c * 64 + j], h1[j], s);
    float mvv = 1.f / (1.f + expf(-s));
    for (int q = 0; q < 9; ++q) {
        float s2 = 0.f;
        for (int j = 0; j < 64; ++j) s2 = fmaf(kW2[(c * 9 + q) * 64 + j], g1[j], s2);
        ktr[b * 576 + q * 64 + c] = lrelu(s2) * mvv;
    }
}

// ---------------------------------------------------------------------------
// Zero row buffer (edge-redirect source for staging).
// ---------------------------------------------------------------------------
__global__ void k_zrow(ushort_t* __restrict__ z) {
    int i = blockIdx.x * 256 + threadIdx.x;  // 2048 threads, 16384 shorts
    *(short8*)(z + (size_t)i * 8) = (short8)0;
}

// ---------------------------------------------------------------------------
// Pack weights, chunk-major.
// wpM: [chunk][row 0..35][lane][8]  rows 0-17: fW1, rows 18-35: cW (row=t*2+ct)
// wp2: [chunk][row 0..17][lane][8]  fW2.
//   element = W[co = ct*32+(lane&31)][ci = chunk*16+(lane>>5)*8+j], tap t
// ---------------------------------------------------------------------------
__global__ void k_pack(const float* __restrict__ w1, const float* __restrict__ w2,
                       const float* __restrict__ w3, ushort_t* __restrict__ wpM,
                       ushort_t* __restrict__ wp2) {
    int idx = blockIdx.x * 256 + threadIdx.x;
    const int NM = 4 * 36 * 512;
    if (idx >= NM + 4 * 18 * 512) return;
    const float* W;
    ushort_t* dst;
    int chunk, row, e;
    if (idx < NM) {
        chunk = idx / (36 * 512);
        int rem = idx % (36 * 512);
        row = rem / 512;
        e = rem % 512;
        W = (row < 18) ? w1 : w3;
        dst = wpM + idx;
        row %= 18;
    } else {
        int i2 = idx - NM;
        chunk = i2 / (18 * 512);
        int rem = i2 % (18 * 512);
        row = rem / 512;
        e = rem % 512;
        W = w2;
        dst = wp2 + i2;
    }
    int lane = e >> 3, j = e & 7;
    int t = row >> 1, ct = row & 1;
    int co = ct * 32 + (lane & 31);
    int ci = chunk * 16 + (lane >> 5) * 8 + j;
    *dst = f2bf(W[(co * 64 + ci) * 9 + t]);
}

// ---------------------------------------------------------------------------
// Transpose x: fp32 NCHW -> bf16 NHWC (round-16 gather version). Block=(b,h).
// ---------------------------------------------------------------------------
__global__ __launch_bounds__(256) void k_tr(const float* __restrict__ x,
                                            ushort_t* __restrict__ xbf) {
    int bid = blockIdx.x;
    int h = bid & 255, b = bid >> 8;
    int t = threadIdx.x;
    for (int it = 0; it < 8; ++it) {
        int idx = t + it * 256;  // (w, g)
        int g = idx & 7, w = idx >> 3;
        const float* src = x + (((size_t)(b * 64 + g * 8) * 256 + h) * 256 + w);
        short8 v;
#pragma unroll
        for (int j = 0; j < 8; ++j) v[j] = (short)f2bf(src[(size_t)j * 65536]);
        *(short8*)(xbf + (((size_t)(b * 256 + h) * 256 + w) * 64 + g * 8)) = v;
    }
}

// ---------------------------------------------------------------------------
// Full-width stage (conv02): 3 rows x 258 pix, 7 x gload_lds16 per wave.
// ---------------------------------------------------------------------------
#define STAGE_X(chunk, xbase)                                                    \
    {                                                                            \
        _Pragma("unroll")                                                        \
        for (int i_ = 0; i_ < 7; ++i_) {                                         \
            int base_ = wv * 390 + i_ * 64;                                      \
            int S_ = base_ + lane;                                               \
            S_ = S_ < CHUNK_SLOTS ? S_ : CHUNK_SLOTS - 1;                        \
            int row_ = (S_ >= 2 * CHUNK_ROW) ? 2 : (S_ >= CHUNK_ROW ? 1 : 0);    \
            int rem_ = S_ - row_ * CHUNK_ROW;                                    \
            int mg_ = rem_ >> 3, sl_ = rem_ & 7;                                 \
            int sp_ = sl_ ^ (mg_ & 7);                                           \
            int p_ = mg_ * 4 + (sp_ >> 1), g_ = sp_ & 1;                         \
            int wsx_ = p_ - 1;                                                   \
            bool edge_ = (unsigned)wsx_ >= 256u;                                 \
            const ushort_t* rp_ = (row_ == 0) ? rb0 : (row_ == 1 ? rb1 : rb2);   \
            const ushort_t* src_ =                                               \
                edge_ ? zv : (rp_ + wsx_ * 64 + (chunk)*16 + g_ * 8);            \
            gload_lds16(src_, xs + (xbase) + (size_t)base_ * 8);                 \
        }                                                                        \
    }

// merged: stage 36-row weight slice (10/wave, rows 36-39 pad dups).
#define STAGE_WM(chunk)                                                          \
    {                                                                            \
        _Pragma("unroll")                                                        \
        for (int i_ = 0; i_ < 10; ++i_) {                                        \
            int row_ = wv * 10 + i_;                                             \
            int rc_ = row_ > 35 ? 35 : row_;                                     \
            gload_lds16(wpM + (size_t)((chunk)*36 + rc_) * 512 + lane * 8,       \
                        xs + (size_t)row_ * 512);                                \
        }                                                                        \
    }

// merged compute: A rows 0..17 (fW1) + 18..35 (cW); one B read -> 4 MFMAs.
#define COMPUTE_M()                                                              \
    {                                                                            \
        __builtin_amdgcn_s_setprio(1);                                           \
        _Pragma("unroll")                                                        \
        for (int t_ = 0; t_ < 9; ++t_) {                                         \
            short8 a0 = *(const short8*)(xs + (size_t)(t_ * 2) * 512 + lane * 8);\
            short8 a1 = *(const short8*)(xs + (size_t)(t_ * 2 + 1) * 512 + lane * 8); \
            short8 c0 = *(const short8*)(xs + (size_t)(18 + t_ * 2) * 512 + lane * 8); \
            short8 c1 = *(const short8*)(xs + (size_t)(19 + t_ * 2) * 512 + lane * 8); \
            const int dwx_ = t_ % 3, rr_ = t_ / 3;                               \
            _Pragma("unroll")                                                    \
            for (int pt_ = 0; pt_ < 2; ++pt_) {                                  \
                int p_ = pw0 + pt_ * 32 + l31 + dwx_;                            \
                int mg_ = p_ >> 2;                                               \
                int sl_ = ((p_ & 3) * 2 + lhi) ^ (mg_ & 7);                      \
                short8 bf = *(const short8*)(                                    \
                    xs + XBM + (size_t)(rr_ * CHUNK_ROW + mg_ * 8 + sl_) * 8);   \
                accA[0][pt_] = __builtin_amdgcn_mfma_f32_32x32x16_bf16(          \
                    a0, bf, accA[0][pt_], 0, 0, 0);                              \
                accA[1][pt_] = __builtin_amdgcn_mfma_f32_32x32x16_bf16(          \
                    a1, bf, accA[1][pt_], 0, 0, 0);                              \
                accC[0][pt_] = __builtin_amdgcn_mfma_f32_32x32x16_bf16(          \
                    c0, bf, accC[0][pt_], 0, 0, 0);                              \
                accC[1][pt_] = __builtin_amdgcn_mfma_f32_32x32x16_bf16(          \
                    c1, bf, accC[1][pt_], 0, 0, 0);                              \
            }                                                                    \
        }                                                                        \
        __builtin_amdgcn_s_setprio(0);                                           \
    }

// ---------------------------------------------------------------------------
// Merged conv0+conv2 (round-16 verbatim). Block = (b,h) XCD-swizzled.
// accA: fW1+fb1+leaky -> f1 bf16 NHWC. accC: cW+cb -> fp32 NCHW (d_out).
// ---------------------------------------------------------------------------
__global__ __launch_bounds__(256, 2) void k_conv02(
    const ushort_t* __restrict__ in, const ushort_t* __restrict__ zv,
    const ushort_t* __restrict__ wpM, const float* __restrict__ ba,
    const float* __restrict__ bc, ushort_t* __restrict__ f1out,
    float* __restrict__ cres) {
    extern __shared__ __align__(16) ushort_t xs[];  // [W 40 rows][X 1632 slots]
    const int tid = threadIdx.x;
    const int lane = tid & 63;
    const int wv = tid >> 6;  // 0..3
    const unsigned bid = blockIdx.x;
    const unsigned L = (bid & 7u) * 512u + (bid >> 3);  // 4096 = 8*512 bijective
    const int h = L & 255, b = L >> 8;
    const int l31 = lane & 31, lhi = lane >> 5;
    const int pw0 = wv * 64;

    const ushort_t* rb0 = (h > 0)   ? in + ((size_t)(b * 256 + h - 1)) * 16384 : zv;
    const ushort_t* rb1 =             in + ((size_t)(b * 256 + h)) * 16384;
    const ushort_t* rb2 = (h < 255) ? in + ((size_t)(b * 256 + h + 1)) * 16384 : zv;

    f32x16 accA[2][2], accC[2][2];
#pragma unroll
    for (int a = 0; a < 2; ++a)
#pragma unroll
        for (int c = 0; c < 2; ++c) { accA[a][c] = (f32x16)0.0f; accC[a][c] = (f32x16)0.0f; }

#pragma unroll
    for (int ch = 0; ch < 4; ++ch) {
        STAGE_WM(ch);
        STAGE_X(ch, XBM);
        VMCNT(0);
        RBAR(); SCHED0();
        COMPUTE_M();
        RBAR();  // protect W+X before next chunk's staging
    }

    // Epilogues. D layout: col(pix)=lane&31, row(co)=(reg&3)+8*(reg>>2)+4*(lane>>5)
    const int co_b = 4 * lhi;
    {   // conv0 -> f1 bf16 NHWC + leaky
        ushort_t* outb = f1out + ((size_t)(b * 256 + h)) * 16384;
#pragma unroll
        for (int ct = 0; ct < 2; ++ct)
#pragma unroll
            for (int pt = 0; pt < 2; ++pt) {
                int pix = pw0 + pt * 32 + l31;
                ushort_t* po = outb + (size_t)pix * 64 + ct * 32 + co_b;
#pragma unroll
                for (int q = 0; q < 4; ++q) {
                    float4v bv = *(const float4v*)(ba + ct * 32 + co_b + 8 * q);
                    short4v sv;
#pragma unroll
                    for (int m = 0; m < 4; ++m) {
                        float v = lrelu(accA[ct][pt][q * 4 + m] + bv[m]);
                        sv[m] = (short)f2bf(v);
                    }
                    *(short4v*)(po + 8 * q) = sv;
                }
            }
    }
    {   // conv2 -> d_out fp32 NCHW + cb
        float* pb = cres + (((size_t)b * 64) << 16) + h * 256;
#pragma unroll
        for (int ct = 0; ct < 2; ++ct)
#pragma unroll
            for (int pt = 0; pt < 2; ++pt) {
                int pix = pw0 + pt * 32 + l31;
#pragma unroll
                for (int q = 0; q < 4; ++q) {
                    float4v bv = *(const float4v*)(bc + ct * 32 + co_b + 8 * q);
#pragma unroll
                    for (int m = 0; m < 4; ++m) {
                        int c = ct * 32 + co_b + 8 * q + m;
                        pb[((size_t)c << 16) + pix] = accC[ct][pt][q * 4 + m] + bv[m];
                    }
                }
            }
    }
}

// ---------------------------------------------------------------------------
// conv1 HALF-WIDTH: block = (b,h,half), 4 waves x (64co x 32px).
// W slice single-buffered (5/wave), X half-chunks double-buffered (4/wave):
// 9 loads/wave/chunk -> counted VMCNT(4). LDS 48KB -> 3 blocks/CU.
// ---------------------------------------------------------------------------
#define STAGE_WH(chunk)                                                          \
    {                                                                            \
        _Pragma("unroll")                                                        \
        for (int i_ = 0; i_ < 5; ++i_) {                                         \
            int row_ = wv * 5 + i_;                                              \
            int rc_ = row_ > 17 ? 17 : row_;                                     \
            gload_lds16(wp2 + (size_t)((chunk)*18 + rc_) * 512 + lane * 8,       \
                        xs + (size_t)row_ * 512);                                \
        }                                                                        \
    }

#define STAGE_XH(chunk, xbase)                                                   \
    {                                                                            \
        _Pragma("unroll")                                                        \
        for (int i_ = 0; i_ < 4; ++i_) {                                         \
            int base_ = wv * 198 + i_ * 64;                                      \
            int S_ = base_ + lane;                                               \
            S_ = S_ < HCHS ? S_ : HCHS - 1;                                      \
            int row_ = (S_ >= 2 * HROW) ? 2 : (S_ >= HROW ? 1 : 0);              \
            int rem_ = S_ - row_ * HROW;                                         \
            int mg_ = rem_ >> 3, sl_ = rem_ & 7;                                 \
            int sp_ = sl_ ^ (mg_ & 7);                                           \
            int p_ = mg_ * 4 + (sp_ >> 1), g_ = sp_ & 1;                         \
            int wsx_ = w0 - 1 + p_;                                              \
            bool edge_ = (unsigned)wsx_ >= 256u;                                 \
            const ushort_t* rp_ = (row_ == 0) ? rb0 : (row_ == 1 ? rb1 : rb2);   \
            const ushort_t* src_ =                                               \
                edge_ ? zv : (rp_ + wsx_ * 64 + (chunk)*16 + g_ * 8);            \
            gload_lds16(src_, xs + (xbase) + (size_t)base_ * 8);                 \
        }                                                                        \
    }

#define COMPUTE_H(xbase)                                                         \
    {                                                                            \
        __builtin_amdgcn_s_setprio(1);                                           \
        _Pragma("unroll")                                                        \
        for (int t_ = 0; t_ < 9; ++t_) {                                         \
            short8 a0 = *(const short8*)(xs + (size_t)(t_ * 2) * 512 + lane * 8);\
            short8 a1 = *(const short8*)(xs + (size_t)(t_ * 2 + 1) * 512 + lane * 8); \
            const int dwx_ = t_ % 3, rr_ = t_ / 3;                               \
            int p_ = wv * 32 + l31 + dwx_;                                       \
            int mg_ = p_ >> 2;                                                   \
            int sl_ = ((p_ & 3) * 2 + lhi) ^ (mg_ & 7);                          \
            short8 bf = *(const short8*)(                                        \
                xs + (xbase) + (size_t)(rr_ * HROW + mg_ * 8 + sl_) * 8);        \
            acc[0] = __builtin_amdgcn_mfma_f32_32x32x16_bf16(a0, bf, acc[0], 0, 0, 0); \
            acc[1] = __builtin_amdgcn_mfma_f32_32x32x16_bf16(a1, bf, acc[1], 0, 0, 0); \
        }                                                                        \
        __builtin_amdgcn_s_setprio(0);                                           \
    }

__global__ __launch_bounds__(256, 3) void k_conv1(
    const ushort_t* __restrict__ in, const ushort_t* __restrict__ zv,
    const ushort_t* __restrict__ wp2, const float* __restrict__ bias,
    ushort_t* __restrict__ outp) {
    extern __shared__ __align__(16) ushort_t xs[];  // [W 20r][xh0][xh1]
    const int tid = threadIdx.x;
    const int lane = tid & 63;
    const int wv = tid >> 6;  // 0..3
    const unsigned bid = blockIdx.x;
    const unsigned L = (bid & 7u) * 1024u + (bid >> 3);  // 8192 = 8*1024
    const int half = L & 1, h = (L >> 1) & 255, b = L >> 9;
    const int w0 = half * 128;
    const int l31 = lane & 31, lhi = lane >> 5;

    const ushort_t* rb0 = (h > 0)   ? in + ((size_t)(b * 256 + h - 1)) * 16384 : zv;
    const ushort_t* rb1 =             in + ((size_t)(b * 256 + h)) * 16384;
    const ushort_t* rb2 = (h < 255) ? in + ((size_t)(b * 256 + h + 1)) * 16384 : zv;

    f32x16 acc[2];
    acc[0] = (f32x16)0.0f;
    acc[1] = (f32x16)0.0f;

    // FIFO/wave: W0(5) X0(4) X1(4) | vm4 C0 | W1(5) X2(4) vm4 C1 |
    //            W2(5) X3(4) vm4 C2 | W3(5) vm0 C3
    STAGE_WH(0);
    STAGE_XH(0, HXB0);
    STAGE_XH(1, HXB1);
    VMCNT(4);   // retire W0+X0; X1 in flight
    RBAR(); SCHED0();
    COMPUTE_H(HXB0);
    RBAR();     // all waves done with W0 + xh0
    STAGE_WH(1); STAGE_XH(2, HXB0);
    VMCNT(4);   // retire X1+W1; X2 in flight
    RBAR(); SCHED0();
    COMPUTE_H(HXB1);
    RBAR();
    STAGE_WH(2); STAGE_XH(3, HXB1);
    VMCNT(4);   // retire X2+W2; X3 in flight
    RBAR(); SCHED0();
    COMPUTE_H(HXB0);
    RBAR();
    STAGE_WH(3);
    VMCNT(0);
    RBAR(); SCHED0();
    COMPUTE_H(HXB1);

    const int co_b = 4 * lhi;
    const int pix = wv * 32 + l31;  // local within half
    // bf16 NCHW + leaky
    ushort_t* pb = outp + (((size_t)b * 64) << 16) + h * 256 + w0;
#pragma unroll
    for (int ct = 0; ct < 2; ++ct)
#pragma unroll
        for (int q = 0; q < 4; ++q) {
            float4v bv = *(const float4v*)(bias + ct * 32 + co_b + 8 * q);
#pragma unroll
            for (int m = 0; m < 4; ++m) {
                int c = ct * 32 + co_b + 8 * q + m;
                float v = lrelu(acc[ct][q * 4 + m] + bv[m]);
                pb[((size_t)c << 16) + pix] = f2bf(v);
            }
        }
}

// ---------------------------------------------------------------------------
// Final depthwise: out[b][c][h][w] += sum_tap ktr[b][tap][c] * f2[b][c][h'][w']
// Block = (b, c, 8-row band); f2 is bf16 NCHW. High occupancy, ~roofline.
// ---------------------------------------------------------------------------
__global__ __launch_bounds__(256) void k_fin(const ushort_t* __restrict__ f2,
                                             const float* __restrict__ ktr,
                                             float* __restrict__ out) {
    __shared__ __align__(16) ushort_t s[10 * 272];
    const unsigned bid = blockIdx.x;
    const unsigned L = (bid & 7u) * 4096u + (bid >> 3);  // bijective, 32768=8*4096
    const int hb = L & 31, c = (L >> 5) & 63, b = L >> 11;
    const int h0 = hb * 8;
    const int w = threadIdx.x;

    const ushort_t* f2c = f2 + (((size_t)(b * 64 + c)) << 16);
    for (int i = w; i < 320; i += 256) {
        int r = i >> 5, seg = i & 31;
        int hs = h0 - 1 + r;
        short8 v = (short8)0;
        if ((unsigned)hs < 256u) v = *(const short8*)(f2c + hs * 256 + seg * 8);
        *(short8*)(&s[r * 272 + 8 + seg * 8]) = v;
        if (seg == 0) s[r * 272 + 7] = 0;
        if (seg == 31) s[r * 272 + 264] = 0;
    }
    __syncthreads();

    float kv[9];
#pragma unroll
    for (int t9 = 0; t9 < 9; ++t9) kv[t9] = ktr[b * 576 + t9 * 64 + c];

    float lv[10], cv[10], rv[10];
#pragma unroll
    for (int r = 0; r < 10; ++r) {
        lv[r] = bf2f(s[r * 272 + 7 + w]);
        cv[r] = bf2f(s[r * 272 + 8 + w]);
        rv[r] = bf2f(s[r * 272 + 9 + w]);
    }

    float* ob = out + (((size_t)(b * 64 + c)) << 16) + h0 * 256 + w;
#pragma unroll
    for (int rr = 0; rr < 8; ++rr) {
        float dwv = 0.f;
#pragma unroll
        for (int r3 = 0; r3 < 3; ++r3) {
            dwv = fmaf(kv[r3 * 3 + 0], lv[rr + r3], dwv);
            dwv = fmaf(kv[r3 * 3 + 1], cv[rr + r3], dwv);
            dwv = fmaf(kv[r3 * 3 + 2], rv[rr + r3], dwv);
        }
        float* po = ob + rr * 256;
        *po = *po + dwv;
    }
}

// ---------------------------------------------------------------------------
extern "C" void kernel_launch(void* const* d_in, const int* in_sizes, int n_in,
                              void* d_out, int out_size, void* d_ws, size_t ws_size,
                              hipStream_t stream) {
    const float* x   = (const float*)d_in[0];
    const float* t   = (const float*)d_in[1];
    const float* tW1 = (const float*)d_in[2];
    const float* tW2 = (const float*)d_in[3];
    const float* fW1 = (const float*)d_in[4];
    const float* fb1 = (const float*)d_in[5];
    const float* fW2 = (const float*)d_in[6];
    const float* fb2 = (const float*)d_in[7];
    const float* kW1 = (const float*)d_in[8];
    const float* kW2 = (const float*)d_in[9];
    const float* cW  = (const float*)d_in[10];
    const float* cb  = (const float*)d_in[11];

    // ws: [ktr 36K @0][wpM 144K @65536][wp2 72K @212992][zv 32K @294912]
    //     [R1 128MB @512K]: xbf (until conv02 done), then f2
    //     [R2 128MB @512K+128MB]: f1
    char* ws = (char*)d_ws;
    float*    ktr  = (float*)ws;
    ushort_t* wpM  = (ushort_t*)(ws + 65536);
    ushort_t* wp2  = wpM + 4 * 36 * 512;
    ushort_t* zv   = (ushort_t*)(ws + 294912);
    ushort_t* xbf  = (ushort_t*)(ws + (512u << 10));                       // R1
    ushort_t* f1bf = (ushort_t*)(ws + (512u << 10) + ((size_t)128 << 20)); // R2
    ushort_t* f2n  = xbf;  // R1 reused: xbf dead after k_conv02
    float*    out  = (float*)d_out;

    hipFuncSetAttribute(reinterpret_cast<const void*>(&k_conv02),
                        hipFuncAttributeMaxDynamicSharedMemorySize, DYN02);
    hipFuncSetAttribute(reinterpret_cast<const void*>(&k_conv1),
                        hipFuncAttributeMaxDynamicSharedMemorySize, DYN1);

    k_tiny<<<dim3(16), dim3(64), 0, stream>>>(t, tW1, tW2, kW1, kW2, ktr);
    k_zrow<<<dim3(8), dim3(256), 0, stream>>>(zv);
    k_pack<<<dim3((4 * 36 * 512 + 4 * 18 * 512 + 255) / 256), dim3(256), 0, stream>>>(
        fW1, fW2, cW, wpM, wp2);
    k_tr<<<dim3(4096), dim3(256), 0, stream>>>(x, xbf);

    // conv02: x -> f1 (bf16 NHWC, R2) + d_out (fp32 NCHW, +cb);
    // conv1: f1 -> f2 (bf16 NCHW, R1); k_fin: out += dw(f2)*gate.
    k_conv02<<<dim3(4096), dim3(256), DYN02, stream>>>(
        xbf, zv, wpM, fb1, cb, f1bf, out);
    k_conv1<<<dim3(8192), dim3(256), DYN1, stream>>>(f1bf, zv, wp2, fb2, f2n);
    k_fin<<<dim3(32768), dim3(256), 0, stream>>>(f2n, ktr, out);
}

// Round 19
// 581.540 us; speedup vs baseline: 1.0338x; 1.0231x over previous
//
#include <hip/hip_runtime.h>
#include <cstdint>

// B=16, C=64, H=W=256. 3x3 convs via bf16 MFMA implicit GEMM.
// Round 19: conv kernels = round 16 verbatim (best measured: conv02 merged
// 2-phase 67KB/2blk + conv1 W-single/X-double counted-vmcnt 72.7KB/2blk +
// k_fin). New: k_setup merges tiny/zrow/pack (one dispatch); k_tr rebuilt
// with an LDS tile (coalesced 256B fp32 reads + contiguous NHWC writes).
using short8  = __attribute__((ext_vector_type(8))) short;
using short4v = __attribute__((ext_vector_type(4))) short;
using f32x16  = __attribute__((ext_vector_type(16))) float;
using float4v = __attribute__((ext_vector_type(4))) float;
typedef unsigned short ushort_t;

#define CHUNK_ROW 520       // 65 macro-groups x 8 slots (16 ci)
#define CHUNK_SLOTS 1560    // 3 rows
#define BUF_SLOTS 1632      // padded (stage stripes overrun to 1617)
#define XSHW (BUF_SLOTS * 8)   // shorts per pixel buffer = 13056
#define WSHW (20 * 512)        // conv1: weight buffer (18 rows + 2 pad)
#define XB0 WSHW
#define XB1 (WSHW + XSHW)
#define DYN1 ((WSHW + 2 * XSHW) * 2)     // conv1: 72704 B -> 2 blocks/CU
#define WSHM (40 * 512)        // merged: 36 rows + 4 pad = 20480 shorts
#define XBM WSHM               // merged pixel buffer offset (shorts)
#define DYN02 ((WSHM + XSHW) * 2)        // merged: 67072 B -> 2 blocks/CU

__device__ __forceinline__ float lrelu(float x) { return x > 0.f ? x : 0.1f * x; }

__device__ __forceinline__ ushort_t f2bf(float f) {
    union { float f; unsigned u; } v; v.f = f;
    unsigned r = (v.u + 0x7FFFu + ((v.u >> 16) & 1u)) >> 16;
    return (ushort_t)r;
}
__device__ __forceinline__ float bf2f(ushort_t b) {
    union { unsigned u; float f; } v; v.u = ((unsigned)b) << 16; return v.f;
}

// async 16B global -> LDS (dest = wave-uniform base; HW adds lane*16)
__device__ __forceinline__ void gload_lds16(const ushort_t* g, ushort_t* l) {
    __builtin_amdgcn_global_load_lds(
        (const __attribute__((address_space(1))) void*)g,
        (__attribute__((address_space(3))) void*)l, 16, 0, 0);
}

#define VMCNT(n) asm volatile("s_waitcnt vmcnt(" #n ")" ::: "memory")
#define RBAR() __builtin_amdgcn_s_barrier()
#define SCHED0() __builtin_amdgcn_sched_barrier(0)

// ---------------------------------------------------------------------------
// k_setup: one dispatch for weight packing (blocks 0-431), zero-row fill
// (432-439), and the tiny t-branch (440-455).
// wpM: [chunk][row 0..35][lane][8]  rows 0-17: fW1, 18-35: cW (row=t*2+ct)
// wp2: [chunk][row 0..17][lane][8]  fW2.
// ktr[b][tap][c] = leaky(kern) * sigmoid-gate (mv folded in).
// ---------------------------------------------------------------------------
__global__ __launch_bounds__(256) void k_setup(
    const float* __restrict__ t, const float* __restrict__ tW1,
    const float* __restrict__ tW2, const float* __restrict__ kW1,
    const float* __restrict__ kW2, const float* __restrict__ w1,
    const float* __restrict__ w2, const float* __restrict__ w3,
    float* __restrict__ ktr, ushort_t* __restrict__ wpM,
    ushort_t* __restrict__ wp2, ushort_t* __restrict__ zv) {
    __shared__ float h1[64], g1[64];
    const int bid = blockIdx.x;
    const int tid = threadIdx.x;
    if (bid < 432) {
        int idx = bid * 256 + tid;
        const int NM = 4 * 36 * 512;
        if (idx < NM + 4 * 18 * 512) {
            const float* W;
            ushort_t* dst;
            int chunk, row, e;
            if (idx < NM) {
                chunk = idx / (36 * 512);
                int rem = idx % (36 * 512);
                row = rem / 512;
                e = rem % 512;
                W = (row < 18) ? w1 : w3;
                dst = wpM + idx;
                row %= 18;
            } else {
                int i2 = idx - NM;
                chunk = i2 / (18 * 512);
                int rem = i2 % (18 * 512);
                row = rem / 512;
                e = rem % 512;
                W = w2;
                dst = wp2 + i2;
            }
            int lane = e >> 3, j = e & 7;
            int tt = row >> 1, ct = row & 1;
            int co = ct * 32 + (lane & 31);
            int ci = chunk * 16 + (lane >> 5) * 8 + j;
            *dst = f2bf(W[(co * 64 + ci) * 9 + tt]);
        }
    } else if (bid < 440) {
        int i = (bid - 432) * 256 + tid;
        *(short8*)(zv + (size_t)i * 8) = (short8)0;
    } else {
        int b = bid - 440;
        int c = tid;
        if (tid < 64) {
            float ts = t[b];
            h1[c] = lrelu(ts * tW1[c]);
            g1[c] = lrelu(ts * kW1[c]);
        }
        __syncthreads();
        if (tid < 64) {
            float s = 0.f;
            for (int j = 0; j < 64; ++j) s = fmaf(tW2[c * 64 + j], h1[j], s);
            float mvv = 1.f / (1.f + expf(-s));
            for (int q = 0; q < 9; ++q) {
                float s2 = 0.f;
                for (int j = 0; j < 64; ++j)
                    s2 = fmaf(kW2[(c * 9 + q) * 64 + j], g1[j], s2);
                ktr[b * 576 + q * 64 + c] = lrelu(s2) * mvv;
            }
        }
    }
}

// ---------------------------------------------------------------------------
// Transpose x: fp32 NCHW -> bf16 NHWC via LDS tile. Block = (b,h); 4 w-tiles
// of 64. Reads: 256B coalesced per (wave,c); writes: 16B/thread contiguous.
// ---------------------------------------------------------------------------
__global__ __launch_bounds__(256) void k_tr(const float* __restrict__ x,
                                            ushort_t* __restrict__ xbf) {
    __shared__ ushort_t tl[64][66];
    int bid = blockIdx.x;
    int h = bid & 255, b = bid >> 8;
    int t = threadIdx.x;
    int cb = t >> 6;        // wave id 0..3
    int wl = t & 63;        // lane
    for (int wt = 0; wt < 4; ++wt) {
        __syncthreads();
#pragma unroll
        for (int cc = 0; cc < 16; ++cc) {
            int c = cc * 4 + cb;
            float v = x[(((size_t)(b * 64 + c)) << 16) + h * 256 + wt * 64 + wl];
            tl[c][wl] = f2bf(v);
        }
        __syncthreads();
        int g = t & 7, w2 = t >> 3;  // 0..31
#pragma unroll
        for (int half = 0; half < 2; ++half) {
            int w = w2 + half * 32;
            short8 v;
#pragma unroll
            for (int j = 0; j < 8; ++j) v[j] = (short)tl[g * 8 + j][w];
            *(short8*)(xbf + (((size_t)(b * 256 + h) * 256 + wt * 64 + w) * 64 + g * 8)) = v;
        }
    }
}

// ---------------------------------------------------------------------------
// Full-width pixel stage: 3 rows x 258 pix, 7 x gload_lds16 per wave.
// Inverse swizzle baked into per-lane source address.
// ---------------------------------------------------------------------------
#define STAGE_X(chunk, xbase)                                                    \
    {                                                                            \
        _Pragma("unroll")                                                        \
        for (int i_ = 0; i_ < 7; ++i_) {                                         \
            int base_ = wv * 390 + i_ * 64;                                      \
            int S_ = base_ + lane;                                               \
            S_ = S_ < CHUNK_SLOTS ? S_ : CHUNK_SLOTS - 1;                        \
            int row_ = (S_ >= 2 * CHUNK_ROW) ? 2 : (S_ >= CHUNK_ROW ? 1 : 0);    \
            int rem_ = S_ - row_ * CHUNK_ROW;                                    \
            int mg_ = rem_ >> 3, sl_ = rem_ & 7;                                 \
            int sp_ = sl_ ^ (mg_ & 7);                                           \
            int p_ = mg_ * 4 + (sp_ >> 1), g_ = sp_ & 1;                         \
            int wsx_ = p_ - 1;                                                   \
            bool edge_ = (unsigned)wsx_ >= 256u;                                 \
            const ushort_t* rp_ = (row_ == 0) ? rb0 : (row_ == 1 ? rb1 : rb2);   \
            const ushort_t* src_ =                                               \
                edge_ ? zv : (rp_ + wsx_ * 64 + (chunk)*16 + g_ * 8);            \
            gload_lds16(src_, xs + (xbase) + (size_t)base_ * 8);                 \
        }                                                                        \
    }

// conv1: stage 18-row weight slice (5/wave, rows 18-19 pad dups).
#define STAGE_W(chunk)                                                           \
    {                                                                            \
        _Pragma("unroll")                                                        \
        for (int i_ = 0; i_ < 5; ++i_) {                                         \
            int row_ = wv * 5 + i_;                                              \
            int rc_ = row_ > 17 ? 17 : row_;                                     \
            gload_lds16(wp + (size_t)((chunk)*18 + rc_) * 512 + lane * 8,        \
                        xs + (size_t)row_ * 512);                                \
        }                                                                        \
    }

// merged: stage 36-row weight slice (10/wave, rows 36-39 pad dups).
#define STAGE_WM(chunk)                                                          \
    {                                                                            \
        _Pragma("unroll")                                                        \
        for (int i_ = 0; i_ < 10; ++i_) {                                        \
            int row_ = wv * 10 + i_;                                             \
            int rc_ = row_ > 35 ? 35 : row_;                                     \
            gload_lds16(wpM + (size_t)((chunk)*36 + rc_) * 512 + lane * 8,       \
                        xs + (size_t)row_ * 512);                                \
        }                                                                        \
    }

// conv1 compute: A rows 0..17, B from xbase. Pure-LDS cluster.
#define COMPUTE(xbase)                                                           \
    {                                                                            \
        __builtin_amdgcn_s_setprio(1);                                           \
        _Pragma("unroll")                                                        \
        for (int t_ = 0; t_ < 9; ++t_) {                                         \
            short8 a0 = *(const short8*)(xs + (size_t)(t_ * 2) * 512 + lane * 8);\
            short8 a1 = *(const short8*)(xs + (size_t)(t_ * 2 + 1) * 512 + lane * 8); \
            const int dwx_ = t_ % 3, rr_ = t_ / 3;                               \
            _Pragma("unroll")                                                    \
            for (int pt_ = 0; pt_ < 2; ++pt_) {                                  \
                int p_ = pw0 + pt_ * 32 + l31 + dwx_;                            \
                int mg_ = p_ >> 2;                                               \
                int sl_ = ((p_ & 3) * 2 + lhi) ^ (mg_ & 7);                      \
                short8 bf = *(const short8*)(                                    \
                    xs + (xbase) + (size_t)(rr_ * CHUNK_ROW + mg_ * 8 + sl_) * 8);\
                acc[0][pt_] = __builtin_amdgcn_mfma_f32_32x32x16_bf16(           \
                    a0, bf, acc[0][pt_], 0, 0, 0);                               \
                acc[1][pt_] = __builtin_amdgcn_mfma_f32_32x32x16_bf16(           \
                    a1, bf, acc[1][pt_], 0, 0, 0);                               \
            }                                                                    \
        }                                                                        \
        __builtin_amdgcn_s_setprio(0);                                           \
    }

// merged compute: A rows 0..17 (fW1) + 18..35 (cW); one B read -> 4 MFMAs.
#define COMPUTE_M()                                                              \
    {                                                                            \
        __builtin_amdgcn_s_setprio(1);                                           \
        _Pragma("unroll")                                                        \
        for (int t_ = 0; t_ < 9; ++t_) {                                         \
            short8 a0 = *(const short8*)(xs + (size_t)(t_ * 2) * 512 + lane * 8);\
            short8 a1 = *(const short8*)(xs + (size_t)(t_ * 2 + 1) * 512 + lane * 8); \
            short8 c0 = *(const short8*)(xs + (size_t)(18 + t_ * 2) * 512 + lane * 8); \
            short8 c1 = *(const short8*)(xs + (size_t)(19 + t_ * 2) * 512 + lane * 8); \
            const int dwx_ = t_ % 3, rr_ = t_ / 3;                               \
            _Pragma("unroll")                                                    \
            for (int pt_ = 0; pt_ < 2; ++pt_) {                                  \
                int p_ = pw0 + pt_ * 32 + l31 + dwx_;                            \
                int mg_ = p_ >> 2;                                               \
                int sl_ = ((p_ & 3) * 2 + lhi) ^ (mg_ & 7);                      \
                short8 bf = *(const short8*)(                                    \
                    xs + XBM + (size_t)(rr_ * CHUNK_ROW + mg_ * 8 + sl_) * 8);   \
                accA[0][pt_] = __builtin_amdgcn_mfma_f32_32x32x16_bf16(          \
                    a0, bf, accA[0][pt_], 0, 0, 0);                              \
                accA[1][pt_] = __builtin_amdgcn_mfma_f32_32x32x16_bf16(          \
                    a1, bf, accA[1][pt_], 0, 0, 0);                              \
                accC[0][pt_] = __builtin_amdgcn_mfma_f32_32x32x16_bf16(          \
                    c0, bf, accC[0][pt_], 0, 0, 0);                              \
                accC[1][pt_] = __builtin_amdgcn_mfma_f32_32x32x16_bf16(          \
                    c1, bf, accC[1][pt_], 0, 0, 0);                              \
            }                                                                    \
        }                                                                        \
        __builtin_amdgcn_s_setprio(0);                                           \
    }

// ---------------------------------------------------------------------------
// Merged conv0+conv2 (round-16 verbatim). Block = (b,h) XCD-swizzled.
// accA: fW1+fb1+leaky -> f1 bf16 NHWC. accC: cW+cb -> fp32 NCHW (d_out).
// ---------------------------------------------------------------------------
__global__ __launch_bounds__(256, 2) void k_conv02(
    const ushort_t* __restrict__ in, const ushort_t* __restrict__ zv,
    const ushort_t* __restrict__ wpM, const float* __restrict__ ba,
    const float* __restrict__ bc, ushort_t* __restrict__ f1out,
    float* __restrict__ cres) {
    extern __shared__ __align__(16) ushort_t xs[];  // [W 40 rows][X 1632 slots]
    const int tid = threadIdx.x;
    const int lane = tid & 63;
    const int wv = tid >> 6;  // 0..3
    const unsigned bid = blockIdx.x;
    const unsigned L = (bid & 7u) * 512u + (bid >> 3);  // 4096 = 8*512 bijective
    const int h = L & 255, b = L >> 8;
    const int l31 = lane & 31, lhi = lane >> 5;
    const int pw0 = wv * 64;

    const ushort_t* rb0 = (h > 0)   ? in + ((size_t)(b * 256 + h - 1)) * 16384 : zv;
    const ushort_t* rb1 =             in + ((size_t)(b * 256 + h)) * 16384;
    const ushort_t* rb2 = (h < 255) ? in + ((size_t)(b * 256 + h + 1)) * 16384 : zv;

    f32x16 accA[2][2], accC[2][2];
#pragma unroll
    for (int a = 0; a < 2; ++a)
#pragma unroll
        for (int c = 0; c < 2; ++c) { accA[a][c] = (f32x16)0.0f; accC[a][c] = (f32x16)0.0f; }

#pragma unroll
    for (int ch = 0; ch < 4; ++ch) {
        STAGE_WM(ch);
        STAGE_X(ch, XBM);
        VMCNT(0);
        RBAR(); SCHED0();
        COMPUTE_M();
        RBAR();  // protect W+X before next chunk's staging
    }

    // Epilogues. D layout: col(pix)=lane&31, row(co)=(reg&3)+8*(reg>>2)+4*(lane>>5)
    const int co_b = 4 * lhi;
    {   // conv0 -> f1 bf16 NHWC + leaky
        ushort_t* outb = f1out + ((size_t)(b * 256 + h)) * 16384;
#pragma unroll
        for (int ct = 0; ct < 2; ++ct)
#pragma unroll
            for (int pt = 0; pt < 2; ++pt) {
                int pix = pw0 + pt * 32 + l31;
                ushort_t* po = outb + (size_t)pix * 64 + ct * 32 + co_b;
#pragma unroll
                for (int q = 0; q < 4; ++q) {
                    float4v bv = *(const float4v*)(ba + ct * 32 + co_b + 8 * q);
                    short4v sv;
#pragma unroll
                    for (int m = 0; m < 4; ++m) {
                        float v = lrelu(accA[ct][pt][q * 4 + m] + bv[m]);
                        sv[m] = (short)f2bf(v);
                    }
                    *(short4v*)(po + 8 * q) = sv;
                }
            }
    }
    {   // conv2 -> d_out fp32 NCHW + cb
        float* pb = cres + (((size_t)b * 64) << 16) + h * 256;
#pragma unroll
        for (int ct = 0; ct < 2; ++ct)
#pragma unroll
            for (int pt = 0; pt < 2; ++pt) {
                int pix = pw0 + pt * 32 + l31;
#pragma unroll
                for (int q = 0; q < 4; ++q) {
                    float4v bv = *(const float4v*)(bc + ct * 32 + co_b + 8 * q);
#pragma unroll
                    for (int m = 0; m < 4; ++m) {
                        int c = ct * 32 + co_b + 8 * q + m;
                        pb[((size_t)c << 16) + pix] = accC[ct][pt][q * 4 + m] + bv[m];
                    }
                }
            }
    }
}

// ---------------------------------------------------------------------------
// conv1 (round-16 verbatim): W single-buffered (re-staged per chunk in the
// FIFO), X double-buffered, counted VMCNT(7). 72.7KB -> 2 blocks/CU.
// bf16 NHWC in -> leaky -> bf16 NCHW out.
// ---------------------------------------------------------------------------
__global__ __launch_bounds__(256, 2) void k_conv1(
    const ushort_t* __restrict__ in, const ushort_t* __restrict__ zv,
    const ushort_t* __restrict__ wp, const float* __restrict__ bias,
    ushort_t* __restrict__ outp) {
    extern __shared__ __align__(16) ushort_t xs[];  // [W 20r][xb0][xb1]
    const int tid = threadIdx.x;
    const int lane = tid & 63;
    const int wv = tid >> 6;  // 0..3
    const unsigned bid = blockIdx.x;
    const unsigned L = (bid & 7u) * 512u + (bid >> 3);
    const int h = L & 255, b = L >> 8;
    const int l31 = lane & 31, lhi = lane >> 5;
    const int pw0 = wv * 64;

    const ushort_t* rb0 = (h > 0)   ? in + ((size_t)(b * 256 + h - 1)) * 16384 : zv;
    const ushort_t* rb1 =             in + ((size_t)(b * 256 + h)) * 16384;
    const ushort_t* rb2 = (h < 255) ? in + ((size_t)(b * 256 + h + 1)) * 16384 : zv;

    f32x16 acc[2][2];
#pragma unroll
    for (int a = 0; a < 2; ++a)
#pragma unroll
        for (int c = 0; c < 2; ++c) acc[a][c] = (f32x16)0.0f;

    STAGE_W(0);
    STAGE_X(0, XB0);
    STAGE_X(1, XB1);
    VMCNT(7);   // retire W0+X0; X1 in flight
    RBAR(); SCHED0();
    COMPUTE(XB0);
    RBAR();     // all waves done with W0 + xb0
    STAGE_W(1); STAGE_X(2, XB0);
    VMCNT(7);   // retire X1+W1; X2 in flight
    RBAR(); SCHED0();
    COMPUTE(XB1);
    RBAR();
    STAGE_W(2); STAGE_X(3, XB1);
    VMCNT(7);
    RBAR(); SCHED0();
    COMPUTE(XB0);
    RBAR();
    STAGE_W(3);
    VMCNT(0);
    RBAR(); SCHED0();
    COMPUTE(XB1);

    const int co_b = 4 * lhi;
    // bf16 NCHW + leaky
    ushort_t* pb = outp + (((size_t)b * 64) << 16) + h * 256;
#pragma unroll
    for (int ct = 0; ct < 2; ++ct)
#pragma unroll
        for (int pt = 0; pt < 2; ++pt) {
            int pix = pw0 + pt * 32 + l31;
#pragma unroll
            for (int q = 0; q < 4; ++q) {
                float4v bv = *(const float4v*)(bias + ct * 32 + co_b + 8 * q);
#pragma unroll
                for (int m = 0; m < 4; ++m) {
                    int c = ct * 32 + co_b + 8 * q + m;
                    float v = lrelu(acc[ct][pt][q * 4 + m] + bv[m]);
                    pb[((size_t)c << 16) + pix] = f2bf(v);
                }
            }
        }
}

// ---------------------------------------------------------------------------
// Final depthwise: out[b][c][h][w] += sum_tap ktr[b][tap][c] * f2[b][c][h'][w']
// Block = (b, c, 8-row band); f2 is bf16 NCHW. High occupancy, ~roofline.
// ---------------------------------------------------------------------------
__global__ __launch_bounds__(256) void k_fin(const ushort_t* __restrict__ f2,
                                             const float* __restrict__ ktr,
                                             float* __restrict__ out) {
    __shared__ __align__(16) ushort_t s[10 * 272];
    const unsigned bid = blockIdx.x;
    const unsigned L = (bid & 7u) * 4096u + (bid >> 3);  // bijective, 32768=8*4096
    const int hb = L & 31, c = (L >> 5) & 63, b = L >> 11;
    const int h0 = hb * 8;
    const int w = threadIdx.x;

    const ushort_t* f2c = f2 + (((size_t)(b * 64 + c)) << 16);
    for (int i = w; i < 320; i += 256) {
        int r = i >> 5, seg = i & 31;
        int hs = h0 - 1 + r;
        short8 v = (short8)0;
        if ((unsigned)hs < 256u) v = *(const short8*)(f2c + hs * 256 + seg * 8);
        *(short8*)(&s[r * 272 + 8 + seg * 8]) = v;
        if (seg == 0) s[r * 272 + 7] = 0;
        if (seg == 31) s[r * 272 + 264] = 0;
    }
    __syncthreads();

    float kv[9];
#pragma unroll
    for (int t9 = 0; t9 < 9; ++t9) kv[t9] = ktr[b * 576 + t9 * 64 + c];

    float lv[10], cv[10], rv[10];
#pragma unroll
    for (int r = 0; r < 10; ++r) {
        lv[r] = bf2f(s[r * 272 + 7 + w]);
        cv[r] = bf2f(s[r * 272 + 8 + w]);
        rv[r] = bf2f(s[r * 272 + 9 + w]);
    }

    float* ob = out + (((size_t)(b * 64 + c)) << 16) + h0 * 256 + w;
#pragma unroll
    for (int rr = 0; rr < 8; ++rr) {
        float dwv = 0.f;
#pragma unroll
        for (int r3 = 0; r3 < 3; ++r3) {
            dwv = fmaf(kv[r3 * 3 + 0], lv[rr + r3], dwv);
            dwv = fmaf(kv[r3 * 3 + 1], cv[rr + r3], dwv);
            dwv = fmaf(kv[r3 * 3 + 2], rv[rr + r3], dwv);
        }
        float* po = ob + rr * 256;
        *po = *po + dwv;
    }
}

// ---------------------------------------------------------------------------
extern "C" void kernel_launch(void* const* d_in, const int* in_sizes, int n_in,
                              void* d_out, int out_size, void* d_ws, size_t ws_size,
                              hipStream_t stream) {
    const float* x   = (const float*)d_in[0];
    const float* t   = (const float*)d_in[1];
    const float* tW1 = (const float*)d_in[2];
    const float* tW2 = (const float*)d_in[3];
    const float* fW1 = (const float*)d_in[4];
    const float* fb1 = (const float*)d_in[5];
    const float* fW2 = (const float*)d_in[6];
    const float* fb2 = (const float*)d_in[7];
    const float* kW1 = (const float*)d_in[8];
    const float* kW2 = (const float*)d_in[9];
    const float* cW  = (const float*)d_in[10];
    const float* cb  = (const float*)d_in[11];

    // ws: [ktr 36K @0][wpM 144K @65536][wp2 72K @212992][zv 32K @294912]
    //     [R1 128MB @512K]: xbf (until conv02 done), then f2
    //     [R2 128MB @512K+128MB]: f1
    char* ws = (char*)d_ws;
    float*    ktr  = (float*)ws;
    ushort_t* wpM  = (ushort_t*)(ws + 65536);
    ushort_t* wp2  = wpM + 4 * 36 * 512;
    ushort_t* zv   = (ushort_t*)(ws + 294912);
    ushort_t* xbf  = (ushort_t*)(ws + (512u << 10));                       // R1
    ushort_t* f1bf = (ushort_t*)(ws + (512u << 10) + ((size_t)128 << 20)); // R2
    ushort_t* f2n  = xbf;  // R1 reused: xbf dead after k_conv02
    float*    out  = (float*)d_out;

    hipFuncSetAttribute(reinterpret_cast<const void*>(&k_conv02),
                        hipFuncAttributeMaxDynamicSharedMemorySize, DYN02);
    hipFuncSetAttribute(reinterpret_cast<const void*>(&k_conv1),
                        hipFuncAttributeMaxDynamicSharedMemorySize, DYN1);

    k_setup<<<dim3(456), dim3(256), 0, stream>>>(
        t, tW1, tW2, kW1, kW2, fW1, fW2, cW, ktr, wpM, wp2, zv);
    k_tr<<<dim3(4096), dim3(256), 0, stream>>>(x, xbf);

    // conv02: x -> f1 (bf16 NHWC, R2) + d_out (fp32 NCHW, +cb);
    // conv1: f1 -> f2 (bf16 NCHW, R1); k_fin: out += dw(f2)*gate.
    k_conv02<<<dim3(4096), dim3(256), DYN02, stream>>>(
        xbf, zv, wpM, fb1, cb, f1bf, out);
    k_conv1<<<dim3(4096), dim3(256), DYN1, stream>>>(f1bf, zv, wp2, fb2, f2n);
    k_fin<<<dim3(32768), dim3(256), 0, stream>>>(f2n, ktr, out);
}